// Round 21
// baseline (2655.213 us; speedup 1.0000x reference)
//
#include <hip/hip_runtime.h>

#define B_N 16
#define T_N 15
#define CIN 64
#define COUT 128
#define HS 56
#define HWN 3136
#define NSG (16 * 128 * 28 * 28)
#define XP 68   // padded ci stride (16B-aligned b128, bank-spread)

// PROVEN reference model (R10/R14, absmax=0.0):
//   conv: per-output flat sequential FMA chain, k-order (kh, kw, ci-innermost),
//         bias as separate rounded add. fma(+/-0,w,acc)==acc bit-exact.
//   elementwise/scan: per-op rounding, no FMA.
// R14..R20: VALU-busy time constant 0.93ms; stall insensitive to occupancy.
// Hypothesis: hot-loop s_loads (73KB/wave weight stream, k$-miss, lgkm-shared)
// are the structural wait. This round: NO SMEM/VMEM in hot loop — weights
// staged per-tap into LDS, x transposed in LDS, both read as ds_read_b128.
// Chain per output unchanged (tap outer, ci ascending inner).

// ---------- weight transpose: w[co][ci][kh][kw] -> wt4[tap][ci][co]
__global__ void wt_kernel(const float* __restrict__ w, float* __restrict__ wt4) {
    int i = blockIdx.x * 256 + threadIdx.x;  // 0 .. 73727
    if (i >= COUT * 576) return;
    int co = i / 576;
    int r = i - co * 576;      // ci*9 + kh*3 + kw
    int ci = r / 9;
    int kk = r - ci * 9;       // kh*3+kw
    wt4[((size_t)kk * CIN + ci) * COUT + co] = w[i];
}

// ---------- conv: all-LDS hot loop; thread = 4co x 4px ----------
__global__ __launch_bounds__(256) void conv_lds2(
    const float* __restrict__ x, const float* __restrict__ wt4,
    const float* __restrict__ bias, float* __restrict__ obuf,
    int t0, int nz)
{
    __shared__ float xs[100 * XP];   // [xpos][ci], zero halo, 27.2 KB
    __shared__ float wl[64 * XP];    // [co_local][ci], 17.4 KB

    const int bid = blockIdx.x;
    const int z = (bid & 7) * (nz >> 3) + (bid >> 3);   // XCD swizzle

    const int coh = z & 1;            // co half
    int u = z >> 1;
    const int tile = u % 49;
    u /= 49;
    const int b = u & 15;
    const int tc = u >> 4;

    const int h0 = (tile / 7) * 8, w0c = (tile % 7) * 8;
    const int tid = threadIdx.x;

    // ---- stage x transposed [xpos][ci], +0.0f halo ----
    const float* xb = x + ((size_t)(b * T_N + (t0 + tc)) * CIN) * HWN;
    for (int i = tid; i < CIN * 100; i += 256) {
        int ci = i / 100;
        int rem = i - ci * 100;
        int rr = rem / 10, cc = rem - rr * 10;
        int gh = h0 - 1 + rr, gw = w0c - 1 + cc;
        float v = 0.0f;
        if ((unsigned)gh < (unsigned)HS && (unsigned)gw < (unsigned)HS)
            v = xb[(size_t)ci * HWN + gh * HS + gw];
        xs[rem * XP + ci] = v;
    }

    const int cog = tid >> 4;        // 0..15 -> co_local = cog*4..+3
    const int pxg = tid & 15;        // 0..15 -> px = pxg*4..+3
    const int co0l = cog * 4;
    const int px0 = pxg * 4;
    const int lh = px0 >> 3;         // constant row per thread
    const int lw0 = px0 & 7;         // 0 or 4; p stays in-row

    // weight staging indices: thread covers ci = ciw*4..+3? (4 ci x 4 co)
    const int ciw = tid >> 4;        // 0..15
    const int cl4 = tid & 15;        // 0..15 -> co chunk

    float acc[4][4];                 // [j co][p px]
#pragma unroll
    for (int j = 0; j < 4; ++j)
#pragma unroll
        for (int p = 0; p < 4; ++p) acc[j][p] = 0.0f;

    for (int tap = 0; tap < 9; ++tap) {
        __syncthreads();   // xs ready (tap0) / previous compute done
        // stage weights [64ci][64co-half] -> wl[co][ci]
#pragma unroll
        for (int k2 = 0; k2 < 4; ++k2) {
            const int ci = ciw * 4 + k2;
            const float4 wv = *(const float4*)(
                wt4 + ((size_t)tap * CIN + ci) * COUT + coh * 64 + cl4 * 4);
            wl[(cl4 * 4 + 0) * XP + ci] = wv.x;
            wl[(cl4 * 4 + 1) * XP + ci] = wv.y;
            wl[(cl4 * 4 + 2) * XP + ci] = wv.z;
            wl[(cl4 * 4 + 3) * XP + ci] = wv.w;
        }
        __syncthreads();

        const int kh = tap / 3, kw = tap - kh * 3;
        const int xoff = (lh + kh) * 10 + (lw0 + kw);

        for (int c4 = 0; c4 < 16; ++c4) {
            float4 xq[4], wq[4];
#pragma unroll
            for (int p = 0; p < 4; ++p)
                xq[p] = *(const float4*)&xs[(xoff + p) * XP + c4 * 4];
#pragma unroll
            for (int j = 0; j < 4; ++j)
                wq[j] = *(const float4*)&wl[(co0l + j) * XP + c4 * 4];
#pragma unroll
            for (int k = 0; k < 4; ++k) {
#pragma unroll
                for (int j = 0; j < 4; ++j) {
                    const float wjk = (k == 0) ? wq[j].x : (k == 1) ? wq[j].y
                                    : (k == 2) ? wq[j].z : wq[j].w;
#pragma unroll
                    for (int p = 0; p < 4; ++p) {
                        const float xpk = (k == 0) ? xq[p].x : (k == 1) ? xq[p].y
                                        : (k == 2) ? xq[p].z : xq[p].w;
                        acc[j][p] = fmaf(xpk, wjk, acc[j][p]);
                    }
                }
            }
        }
    }

    // bias (separate rounded add) + float4 stores (p contiguous, 16B aligned)
    const size_t btc = (size_t)(tc * 16 + b);
#pragma unroll
    for (int j = 0; j < 4; ++j) {
        const int co = coh * 64 + co0l + j;
        const float bv = bias[co];
        float4 o;
        o.x = __fadd_rn(acc[j][0], bv);
        o.y = __fadd_rn(acc[j][1], bv);
        o.z = __fadd_rn(acc[j][2], bv);
        o.w = __fadd_rn(acc[j][3], bv);
        *(float4*)(obuf + (btc * COUT + co) * HWN
                   + (size_t)(h0 + lh) * HS + (w0c + lw0)) = o;
    }
}

// ---------- recurrence, strict fp32, in-kernel t-loop (UNCHANGED) ----------
__global__ __launch_bounds__(256) void rec32(
    const float* __restrict__ cvbuf, const float* __restrict__ fcw,
    const float* __restrict__ fcb, float* __restrict__ stateD,
    unsigned* __restrict__ stateS, float* __restrict__ out,
    int t0, int nt, int doLoad, int doStore)
{
    const int idx = blockIdx.x * 256 + threadIdx.x;  // 16*128*784 sites
    const int pw = idx % 28;
    int tmp = idx / 28;
    const int ph = tmp % 28;
    tmp /= 28;
    const int co = tmp & 127;
    const int b = tmp >> 7;

    const size_t g = (size_t)idx;

    const float w0 = fcw[0], w1 = fcw[1], w2 = fcw[2], fb = fcb[0];

    float u[4], m3[4], s[4];
    if (doLoad) {
        unsigned sm = stateS[g];
#pragma unroll
        for (int p = 0; p < 4; ++p) {
            u[p] = stateD[(size_t)p * NSG + g];
            m3[p] = stateD[(size_t)(4 + p) * NSG + g];
            s[p] = (float)((sm >> p) & 1u);
        }
    } else {
#pragma unroll
        for (int p = 0; p < 4; ++p) { u[p] = 0.0f; m3[p] = 0.0f; s[p] = 0.0f; }
    }

    const int h0 = ph * 2, wc0 = pw * 2;

    for (int tc = 0; tc < nt; ++tc) {
        const size_t cbase = ((size_t)(tc * 16 + b) * COUT + co) * HWN
                           + (size_t)h0 * HS + wc0;
        const float cv[4] = {cvbuf[cbase], cvbuf[cbase + 1],
                             cvbuf[cbase + HS], cvbuf[cbase + HS + 1]};

#pragma unroll
        for (int p = 0; p < 4; ++p) {
            float e0 = __fadd_rn(__fadd_rn(__fmul_rn(u[p], w0), __fmul_rn(u[p], w1)),
                                 __fmul_rn(u[p], w2));
            float x4 = __fadd_rn(e0, fb);
            float dd = __fmul_rn(0.2f, __fsub_rn(1.0f, s[p]));
            u[p]  = __fadd_rn(__fmul_rn(u[p], dd), cv[p]);
            m3[p] = __fadd_rn(__fmul_rn(m3[p], dd), x4);
            float e1 = __fadd_rn(__fadd_rn(__fmul_rn(u[p], w0), __fmul_rn(u[p], w1)),
                                 __fmul_rn(u[p], w2));
            float mem1 = __fadd_rn(__fadd_rn(e1, fb), m3[p]);
            s[p] = (__fsub_rn(mem1, 0.8f) > 0.0f) ? 1.0f : 0.0f;
        }

        float pooled = 0.25f * (((s[0] + s[1]) + s[2]) + s[3]);
        out[(((size_t)b * T_N + (t0 + tc)) * COUT + co) * 784 + ph * 28 + pw] = pooled;
    }

    if (doStore) {
        unsigned sm = 0;
#pragma unroll
        for (int p = 0; p < 4; ++p) {
            stateD[(size_t)p * NSG + g] = u[p];
            stateD[(size_t)(4 + p) * NSG + g] = m3[p];
            sm |= (s[p] > 0.5f) ? (1u << p) : 0u;
        }
        stateS[g] = sm;
    }
}

extern "C" void kernel_launch(void* const* d_in, const int* in_sizes, int n_in,
                              void* d_out, int out_size, void* d_ws, size_t ws_size,
                              hipStream_t stream) {
    const float* x     = (const float*)d_in[0];
    const float* cw    = (const float*)d_in[1];
    const float* cbias = (const float*)d_in[2];
    const float* fcw   = (const float*)d_in[3];
    const float* fcb   = (const float*)d_in[4];
    float* out = (float*)d_out;

    const size_t wtB   = (size_t)576 * COUT * sizeof(float);        // 294 KB
    const size_t convT = (size_t)B_N * COUT * HWN * sizeof(float);  // 25.69 MB / t
    const size_t statB = (size_t)NSG * 8 * sizeof(float)
                       + (size_t)NSG * sizeof(unsigned);            // ~57.8 MB

    int Tc;
    if (wtB + (size_t)T_N * convT <= ws_size) {
        Tc = T_N;                                   // no state spill needed
    } else if (ws_size > wtB + statB + convT) {
        Tc = (int)((ws_size - wtB - statB) / convT);
        if (Tc > T_N) Tc = T_N;
    } else {
        return;  // ws unusably small
    }

    float* wt4 = (float*)d_ws;
    float* convbuf = (float*)((char*)d_ws + wtB);
    float* stateD = (float*)((char*)d_ws + wtB + (size_t)Tc * convT);
    unsigned* stateS = (unsigned*)((char*)stateD + (size_t)NSG * 8 * sizeof(float));

    wt_kernel<<<(COUT * 576 + 255) / 256, 256, 0, stream>>>(cw, wt4);

    for (int t0 = 0; t0 < T_N; t0 += Tc) {
        const int nt = (T_N - t0 < Tc) ? (T_N - t0) : Tc;
        const int nz = nt * 16 * 49 * 2;            // (btc, tile, co-half)
        conv_lds2<<<nz, 256, 0, stream>>>(x, wt4, cbias, convbuf, t0, nz);
        rec32<<<NSG / 256, 256, 0, stream>>>(
            convbuf, fcw, fcb, stateD, stateS, out,
            t0, nt, t0 > 0 ? 1 : 0, (t0 + nt) < T_N ? 1 : 0);
    }
}